// Round 6
// baseline (658.463 us; speedup 1.0000x reference)
//
#include <hip/hip_runtime.h>

#define NNODES 1700
#define CDIM   256

typedef __attribute__((ext_vector_type(8))) short bf16x8;
typedef __attribute__((ext_vector_type(4))) float f32x4;

__device__ inline float bf2f(unsigned h) { return __uint_as_float(h << 16); }
__device__ inline unsigned short f2bf(float f) {
  unsigned u = __float_as_uint(f);
  u = (u + 0x7FFFu + ((u >> 16) & 1u)) >> 16;  // RNE
  return (unsigned short)u;
}

// ---------------- graph preprocessing (4 launches) ----------------

// K1: zero counters/cursors + transpose 3 weight matrices (f32 [k][n] -> bf16 [n][k])
__global__ __launch_bounds__(256) void prep1(const float* __restrict__ W1,
                                             const float* __restrict__ W2,
                                             const float* __restrict__ W3,
                                             unsigned short* __restrict__ Wt,
                                             int* __restrict__ zb) {
  int i = blockIdx.x * 256 + threadIdx.x;
  if (i < 4 * NNODES) zb[i] = 0;
  if (i < 3 * 65536) {
    int wsel = i >> 16, e = i & 65535;
    const float* W = wsel == 0 ? W1 : (wsel == 1 ? W2 : W3);
    int k = e >> 8, n = e & 255;
    Wt[(wsel << 16) + n * 256 + k] = f2bf(W[e]);
  }
}

// K2: degree count for both graphs. edge_index [2,E]: sources [0..E), dests [E..2E)
__global__ __launch_bounds__(256) void prep2(const int* __restrict__ esp, int Esp,
                                             const int* __restrict__ etm, int Etm,
                                             int* __restrict__ cnt_sp,
                                             int* __restrict__ cnt_tm) {
  int i = blockIdx.x * 256 + threadIdx.x;
  if (i < Esp) {
    atomicAdd(&cnt_sp[esp[Esp + i]], 1);
  } else {
    int k = i - Esp;
    if (k < Etm) atomicAdd(&cnt_tm[etm[Etm + k]], 1);
  }
}

// K3: dinv + exclusive scan of (cnt+1) for both graphs; block 0 = spatial, block 1 = temporal
__global__ __launch_bounds__(1024) void prep3(const int* __restrict__ cnt_sp,
                                              float* __restrict__ dinv_sp,
                                              int* __restrict__ off_sp,
                                              const int* __restrict__ cnt_tm,
                                              float* __restrict__ dinv_tm,
                                              int* __restrict__ off_tm) {
  const int* cnt = blockIdx.x ? cnt_tm : cnt_sp;
  float* dinv = blockIdx.x ? dinv_tm : dinv_sp;
  int* off = blockIdx.x ? off_tm : off_sp;
  __shared__ int s[2048];
  int t = threadIdx.x;
  for (int i = t; i < NNODES; i += 1024) dinv[i] = rsqrtf((float)(cnt[i] + 1));
  for (int i = t; i < 2048; i += 1024) s[i] = (i < NNODES) ? (cnt[i] + 1) : 0;
  for (int d = 1; d < 2048; d <<= 1) {
    __syncthreads();
    int idx = (t + 1) * (d << 1) - 1;
    if (idx < 2048) s[idx] += s[idx - d];
  }
  __syncthreads();
  if (t == 0) s[2047] = 0;
  for (int d = 1024; d >= 1; d >>= 1) {
    __syncthreads();
    int idx = (t + 1) * (d << 1) - 1;
    if (idx < 2048) { int tmp = s[idx - d]; s[idx - d] = s[idx]; s[idx] += tmp; }
  }
  __syncthreads();
  for (int i = t; i <= NNODES; i += 1024) off[i] = s[i];
}

// K4: CSR fill for both graphs (order within a dest's list irrelevant: summed)
__global__ __launch_bounds__(256) void prep4(
    const int* __restrict__ esp, int Esp, const int* __restrict__ etm, int Etm,
    const float* __restrict__ dinv_sp, const int* __restrict__ off_sp,
    int* __restrict__ cur_sp, int* __restrict__ src_sp, float* __restrict__ wgt_sp,
    const float* __restrict__ dinv_tm, const int* __restrict__ off_tm,
    int* __restrict__ cur_tm, int* __restrict__ src_tm, float* __restrict__ wgt_tm) {
  int i = blockIdx.x * 256 + threadIdx.x;
  const int tot_sp = Esp + NNODES;
  if (i < tot_sp) {
    int s, d;
    if (i < Esp) { s = esp[i]; d = esp[Esp + i]; } else { s = d = i - Esp; }
    float w = dinv_sp[s] * dinv_sp[d];
    int p = atomicAdd(&cur_sp[d], 1);
    int idx = off_sp[d] + p;
    src_sp[idx] = s; wgt_sp[idx] = w;
  } else {
    int k = i - tot_sp;
    if (k < Etm + NNODES) {
      int s, d;
      if (k < Etm) { s = etm[k]; d = etm[Etm + k]; } else { s = d = k - Etm; }
      float w = dinv_tm[s] * dinv_tm[d];
      int p = atomicAdd(&cur_tm[d], 1);
      int idx = off_tm[d] + p;
      src_tm[idx] = s; wgt_tm[idx] = w;
    }
  }
}

// ---------------- aggregation: Xa[b,n,:] = sum_e w_e * X[b,src_e,:] ------------------------
// L2-residency re-grid: block = 8 nodes x ONE batch (working set = 1 batch slab,
// 0.87 MB bf16 / 1.74 MB f32 << 4 MB per-XCD L2). Bijective XCD swizzle: XCD k sweeps
// batches [k*8,(k+1)*8) one at a time (213 blocks/batch, all co-resident) -> each slab is
// fetched from HBM once; gather re-reads (deg-fold) served by L2 @34.5 TB/s.
// Slot s = threadIdx>>5 handles node ngrp*8+s, 32 lanes x 8 channels, 2-edge unroll.

template <bool SRCF32>
__global__ __launch_bounds__(256) void agg_kernel(const void* __restrict__ Xp,
                                                  const int* __restrict__ off,
                                                  const int* __restrict__ srcv,
                                                  const float* __restrict__ wv,
                                                  unsigned short* __restrict__ Xa) {
  // grid 13632 = 213 ngrps x 64 batches; 13632/8 = 1704 per XCD
  const int xcd = blockIdx.x & 7, pos = blockIdx.x >> 3;
  const int l = xcd * 1704 + pos;
  const int b = l / 213;            // batches [xcd*8, xcd*8+8)
  const int ngrp = l - b * 213;
  const int n = ngrp * 8 + (threadIdx.x >> 5);
  if (n >= NNODES) return;          // only ngrp==212 upper slots
  const int c = (threadIdx.x & 31) * 8;
  const int beg = off[n], end = off[n + 1];
  const size_t base = (size_t)b * NNODES;

  float a0 = 0.f, a1 = 0.f, a2 = 0.f, a3 = 0.f;
  float a4 = 0.f, a5 = 0.f, a6 = 0.f, a7 = 0.f;
  for (int i = beg; i < end; i += 2) {
    int s0 = srcv[i];
    float w0 = wv[i];
    const bool two = (i + 1 < end);
    int i1 = two ? i + 1 : i;
    int s1 = srcv[i1];
    float w1 = two ? wv[i1] : 0.f;  // weight-0 duplicate gather on odd tail (values finite)
    if (SRCF32) {
      const float* X = (const float*)Xp;
      const float* p0 = X + (base + s0) * CDIM + c;
      const float* p1 = X + (base + s1) * CDIM + c;
      float4 u0 = *(const float4*)p0, u1 = *(const float4*)(p0 + 4);
      float4 v0 = *(const float4*)p1, v1 = *(const float4*)(p1 + 4);
      a0 += w0 * u0.x + w1 * v0.x; a1 += w0 * u0.y + w1 * v0.y;
      a2 += w0 * u0.z + w1 * v0.z; a3 += w0 * u0.w + w1 * v0.w;
      a4 += w0 * u1.x + w1 * v1.x; a5 += w0 * u1.y + w1 * v1.y;
      a6 += w0 * u1.z + w1 * v1.z; a7 += w0 * u1.w + w1 * v1.w;
    } else {
      const unsigned short* X = (const unsigned short*)Xp;
      uint4 u = *(const uint4*)(X + (base + s0) * CDIM + c);
      uint4 v = *(const uint4*)(X + (base + s1) * CDIM + c);
      a0 += w0 * bf2f(u.x & 0xffffu) + w1 * bf2f(v.x & 0xffffu);
      a1 += w0 * bf2f(u.x >> 16)     + w1 * bf2f(v.x >> 16);
      a2 += w0 * bf2f(u.y & 0xffffu) + w1 * bf2f(v.y & 0xffffu);
      a3 += w0 * bf2f(u.y >> 16)     + w1 * bf2f(v.y >> 16);
      a4 += w0 * bf2f(u.z & 0xffffu) + w1 * bf2f(v.z & 0xffffu);
      a5 += w0 * bf2f(u.z >> 16)     + w1 * bf2f(v.z >> 16);
      a6 += w0 * bf2f(u.w & 0xffffu) + w1 * bf2f(v.w & 0xffffu);
      a7 += w0 * bf2f(u.w >> 16)     + w1 * bf2f(v.w >> 16);
    }
  }
  bf16x8 ov;
  ov[0] = (short)f2bf(a0); ov[1] = (short)f2bf(a1);
  ov[2] = (short)f2bf(a2); ov[3] = (short)f2bf(a3);
  ov[4] = (short)f2bf(a4); ov[5] = (short)f2bf(a5);
  ov[6] = (short)f2bf(a6); ov[7] = (short)f2bf(a7);
  *(bf16x8*)(Xa + (base + n) * CDIM + c) = ov;
}

// ---------------- GEMM: out = epilogue( Xa[M][256] @ W ) -----------------------------------
// Barrier-free streaming form (follows the measured winner: independent waves at high
// occupancy beat lockstep pipelines on this workload). No LDS, no barriers, no waitcnt asm.
// Each wave owns a 16x128 tile: A-panel (8 KB) -> regs (8 x 16B/lane, HBM stream);
// B-fragments straight from L2-resident 128 KB Wt (each wave reads its 64 KB W-half);
// 64 MFMA; epilogue. Waves w=0,1 / 2,3 share A rows (L1 hits). 16 waves/CU, all independent.

template <bool FINAL>
__global__ __launch_bounds__(256, 4) void gemm_stream(const unsigned short* __restrict__ A,
                                                      const unsigned short* __restrict__ Wt,
                                                      const float* __restrict__ bias,
                                                      const float* __restrict__ resid,
                                                      void* __restrict__ outp) {
  const int t = threadIdx.x;
  const int lane = t & 63;
  const int w = t >> 6;
  const int lr = lane & 15;
  const int lk = (lane >> 4) * 8;  // k-elem offset within 32-k chunk

  const int rt = blockIdx.x * 2 + (w >> 1);  // row-tile [0,6800): 16 rows
  const int nb = (w & 1) * 128;              // N-half
  const int m0 = rt * 16;

  const unsigned short* arow = A + (size_t)(m0 + lr) * CDIM + lk;
  const unsigned short* brow = Wt + (size_t)(nb + lr) * CDIM + lk;

  bf16x8 a[8];
#pragma unroll
  for (int kc = 0; kc < 8; kc++)
    a[kc] = *(const bf16x8*)(arow + kc * 32);

  f32x4 acc[8] = {};
#pragma unroll
  for (int kc = 0; kc < 8; kc++) {
    bf16x8 b[8];
#pragma unroll
    for (int ni = 0; ni < 8; ni++)
      b[ni] = *(const bf16x8*)(brow + (size_t)ni * 16 * CDIM + kc * 32);
#pragma unroll
    for (int ni = 0; ni < 8; ni++)
      acc[ni] = __builtin_amdgcn_mfma_f32_16x16x32_bf16(a[kc], b[ni], acc[ni], 0, 0, 0);
  }

  // epilogue: +bias, relu, (FINAL: +resid, f32 out). C/D: col=lane&15, row=(lane>>4)*4+r
  const int orow = (lane >> 4) * 4;
#pragma unroll
  for (int ni = 0; ni < 8; ni++) {
    const float bv = bias[nb + ni * 16 + lr];
#pragma unroll
    for (int r = 0; r < 4; r++) {
      const size_t idx = (size_t)(m0 + orow + r) * CDIM + nb + ni * 16 + lr;
      float v = acc[ni][r] + bv;
      if (FINAL) {
        v += resid[idx];
        ((float*)outp)[idx] = fmaxf(v, 0.f);
      } else {
        ((unsigned short*)outp)[idx] = f2bf(fmaxf(v, 0.f));
      }
    }
  }
}

// ---------------- launch ----------------

extern "C" void kernel_launch(void* const* d_in, const int* in_sizes, int n_in,
                              void* d_out, int out_size, void* d_ws, size_t ws_size,
                              hipStream_t stream) {
  const float* x  = (const float*)d_in[0];
  const float* W1 = (const float*)d_in[1];
  const float* b1 = (const float*)d_in[2];
  const float* W2 = (const float*)d_in[3];
  const float* b2 = (const float*)d_in[4];
  const float* W3 = (const float*)d_in[5];
  const float* b3 = (const float*)d_in[6];
  const int* esp = (const int*)d_in[7];
  const int* etm = (const int*)d_in[8];

  const int Esp = in_sizes[7] / 2;
  const int Etm = in_sizes[8] / 2;
  const int B = in_sizes[0] / (NNODES * CDIM);
  const int M = B * NNODES;

  char* ws = (char*)d_ws;
  size_t woff = 0;
  auto alloc = [&](size_t bytes) -> void* {
    void* p = ws + woff;
    woff = (woff + bytes + 255) & ~(size_t)255;
    return p;
  };

  unsigned short* H   = (unsigned short*)alloc((size_t)M * CDIM * 2);  // 55.7 MB bf16
  unsigned short* Act = (unsigned short*)alloc((size_t)M * CDIM * 2);  // 55.7 MB bf16
  unsigned short* Wt  = (unsigned short*)alloc((size_t)3 * CDIM * CDIM * 2);
  int* zero_base = (int*)alloc((size_t)4 * NNODES * sizeof(int));
  int* cnt_sp = zero_base;
  int* cur_sp = zero_base + NNODES;
  int* cnt_tm = zero_base + 2 * NNODES;
  int* cur_tm = zero_base + 3 * NNODES;
  int* off_sp = (int*)alloc((NNODES + 1) * sizeof(int));
  int* off_tm = (int*)alloc((NNODES + 1) * sizeof(int));
  float* dinv_sp = (float*)alloc(NNODES * sizeof(float));
  float* dinv_tm = (float*)alloc(NNODES * sizeof(float));
  int*   src_sp = (int*)alloc((size_t)(Esp + NNODES) * sizeof(int));
  float* wgt_sp = (float*)alloc((size_t)(Esp + NNODES) * sizeof(float));
  int*   src_tm = (int*)alloc((size_t)(Etm + NNODES) * sizeof(int));
  float* wgt_tm = (float*)alloc((size_t)(Etm + NNODES) * sizeof(float));

  // graph preprocessing: 4 launches
  prep1<<<(3 * 65536 + 255) / 256, 256, 0, stream>>>(W1, W2, W3, Wt, zero_base);
  prep2<<<(Esp + Etm + 255) / 256, 256, 0, stream>>>(esp, Esp, etm, Etm, cnt_sp, cnt_tm);
  prep3<<<2, 1024, 0, stream>>>(cnt_sp, dinv_sp, off_sp, cnt_tm, dinv_tm, off_tm);
  prep4<<<(Esp + Etm + 2 * NNODES + 255) / 256, 256, 0, stream>>>(
      esp, Esp, etm, Etm, dinv_sp, off_sp, cur_sp, src_sp, wgt_sp,
      dinv_tm, off_tm, cur_tm, src_tm, wgt_tm);

  dim3 agrid(213 * 64);    // 13632: 213 node-groups x 64 batches, XCD-swizzled in-kernel
  dim3 ggrid(M / 32);      // 3400: each block = 4 waves = 2 row-tiles x 2 N-halves

  // layer 1 (spatial): Xa1 = A_hat x (f32 gather); out1 = relu(Xa1 W1 + b1) -> bf16 H
  agg_kernel<true><<<agrid, 256, 0, stream>>>(x, off_sp, src_sp, wgt_sp, Act);
  gemm_stream<false><<<ggrid, 256, 0, stream>>>(Act, Wt, b1, nullptr, H);
  // layer 2 (temporal)
  agg_kernel<false><<<agrid, 256, 0, stream>>>(H, off_tm, src_tm, wgt_tm, Act);
  gemm_stream<false><<<ggrid, 256, 0, stream>>>(Act, Wt + CDIM * CDIM, b2, nullptr, H);
  // layer 3 (spatial) + residual + relu -> f32 d_out
  agg_kernel<false><<<agrid, 256, 0, stream>>>(H, off_sp, src_sp, wgt_sp, Act);
  gemm_stream<true><<<ggrid, 256, 0, stream>>>(Act, Wt + 2 * CDIM * CDIM, b3, x, d_out);
}

// Round 7
// 420.901 us; speedup vs baseline: 1.5644x; 1.5644x over previous
//
#include <hip/hip_runtime.h>

#define NNODES 1700
#define CDIM   256

typedef __attribute__((ext_vector_type(8))) short bf16x8;
typedef __attribute__((ext_vector_type(4))) float f32x4;

__device__ inline float bf2f(unsigned h) { return __uint_as_float(h << 16); }
__device__ inline unsigned short f2bf(float f) {
  unsigned u = __float_as_uint(f);
  u = (u + 0x7FFFu + ((u >> 16) & 1u)) >> 16;  // RNE
  return (unsigned short)u;
}

__device__ inline void async_copy16(const void* gsrc, void* ldst) {
  __builtin_amdgcn_global_load_lds(
      (const __attribute__((address_space(1))) unsigned int*)gsrc,
      (__attribute__((address_space(3))) unsigned int*)ldst,
      16, 0, 0);
}

// ---------------- graph preprocessing (4 launches) ----------------

__global__ __launch_bounds__(256) void prep1(const float* __restrict__ W1,
                                             const float* __restrict__ W2,
                                             const float* __restrict__ W3,
                                             unsigned short* __restrict__ Wt,
                                             int* __restrict__ zb) {
  int i = blockIdx.x * 256 + threadIdx.x;
  if (i < 4 * NNODES) zb[i] = 0;
  if (i < 3 * 65536) {
    int wsel = i >> 16, e = i & 65535;
    const float* W = wsel == 0 ? W1 : (wsel == 1 ? W2 : W3);
    int k = e >> 8, n = e & 255;
    Wt[(wsel << 16) + n * 256 + k] = f2bf(W[e]);
  }
}

__global__ __launch_bounds__(256) void prep2(const int* __restrict__ esp, int Esp,
                                             const int* __restrict__ etm, int Etm,
                                             int* __restrict__ cnt_sp,
                                             int* __restrict__ cnt_tm) {
  int i = blockIdx.x * 256 + threadIdx.x;
  if (i < Esp) {
    atomicAdd(&cnt_sp[esp[Esp + i]], 1);
  } else {
    int k = i - Esp;
    if (k < Etm) atomicAdd(&cnt_tm[etm[Etm + k]], 1);
  }
}

__global__ __launch_bounds__(1024) void prep3(const int* __restrict__ cnt_sp,
                                              float* __restrict__ dinv_sp,
                                              int* __restrict__ off_sp,
                                              const int* __restrict__ cnt_tm,
                                              float* __restrict__ dinv_tm,
                                              int* __restrict__ off_tm) {
  const int* cnt = blockIdx.x ? cnt_tm : cnt_sp;
  float* dinv = blockIdx.x ? dinv_tm : dinv_sp;
  int* off = blockIdx.x ? off_tm : off_sp;
  __shared__ int s[2048];
  int t = threadIdx.x;
  for (int i = t; i < NNODES; i += 1024) dinv[i] = rsqrtf((float)(cnt[i] + 1));
  for (int i = t; i < 2048; i += 1024) s[i] = (i < NNODES) ? (cnt[i] + 1) : 0;
  for (int d = 1; d < 2048; d <<= 1) {
    __syncthreads();
    int idx = (t + 1) * (d << 1) - 1;
    if (idx < 2048) s[idx] += s[idx - d];
  }
  __syncthreads();
  if (t == 0) s[2047] = 0;
  for (int d = 1024; d >= 1; d >>= 1) {
    __syncthreads();
    int idx = (t + 1) * (d << 1) - 1;
    if (idx < 2048) { int tmp = s[idx - d]; s[idx - d] = s[idx]; s[idx] += tmp; }
  }
  __syncthreads();
  for (int i = t; i <= NNODES; i += 1024) off[i] = s[i];
}

__global__ __launch_bounds__(256) void prep4(
    const int* __restrict__ esp, int Esp, const int* __restrict__ etm, int Etm,
    const float* __restrict__ dinv_sp, const int* __restrict__ off_sp,
    int* __restrict__ cur_sp, int* __restrict__ src_sp, float* __restrict__ wgt_sp,
    const float* __restrict__ dinv_tm, const int* __restrict__ off_tm,
    int* __restrict__ cur_tm, int* __restrict__ src_tm, float* __restrict__ wgt_tm) {
  int i = blockIdx.x * 256 + threadIdx.x;
  const int tot_sp = Esp + NNODES;
  if (i < tot_sp) {
    int s, d;
    if (i < Esp) { s = esp[i]; d = esp[Esp + i]; } else { s = d = i - Esp; }
    float w = dinv_sp[s] * dinv_sp[d];
    int p = atomicAdd(&cur_sp[d], 1);
    int idx = off_sp[d] + p;
    src_sp[idx] = s; wgt_sp[idx] = w;
  } else {
    int k = i - tot_sp;
    if (k < Etm + NNODES) {
      int s, d;
      if (k < Etm) { s = etm[k]; d = etm[Etm + k]; } else { s = d = k - Etm; }
      float w = dinv_tm[s] * dinv_tm[d];
      int p = atomicAdd(&cur_tm[d], 1);
      int idx = off_tm[d] + p;
      src_tm[idx] = s; wgt_tm[idx] = w;
    }
  }
}

// ---------------- aggregation: Xa[b,n,:] = sum_e w_e * X[b,src_e,:] ------------------------
// XCD-confined AND deg-balanced: block = ONE node x small batch-group (all slots share the
// node's degree -> no intra-block imbalance; R6's 8-nodes-per-block version was imbalanced).
// Group sized so the per-XCD live working set (group's batch slabs) fits 4 MB L2:
//   f32 source: 2 batches (2 x 1.74 MB), bf16 source: 4 batches (4 x 0.87 MB).
// Bijective XCD swizzle (blk%8 = XCD): XCD k sweeps its batch-groups sequentially; each slab
// is HBM-fetched ~once, deg-fold re-reads served from L2.

// f32 source: 128 thr = 2 batch-slots x 64 lanes x 4 ch (float4 16B loads)
__global__ __launch_bounds__(128) void agg_f32(const float* __restrict__ X,
                                               const int* __restrict__ off,
                                               const int* __restrict__ srcv,
                                               const float* __restrict__ wv,
                                               unsigned short* __restrict__ Xa) {
  const int perx = gridDim.x >> 3;              // grid = 1700 * (B/2), %8 == 0
  const int gidx = (blockIdx.x & 7) * perx + (blockIdx.x >> 3);
  const int g = gidx / NNODES;                  // batch-group (2 batches)
  const int n = gidx - g * NNODES;
  const int b = g * 2 + (threadIdx.x >> 6);
  const int c = (threadIdx.x & 63) * 4;
  const int beg = off[n], end = off[n + 1];
  const size_t base = (size_t)b * NNODES;

  float a0 = 0.f, a1 = 0.f, a2 = 0.f, a3 = 0.f;
  for (int i = beg; i < end; i += 2) {
    int s0 = srcv[i];
    float w0 = wv[i];
    const bool two = (i + 1 < end);
    int i1 = two ? i + 1 : i;
    int s1 = srcv[i1];
    float w1 = two ? wv[i1] : 0.f;
    float4 u = *(const float4*)(X + (base + s0) * CDIM + c);
    float4 v = *(const float4*)(X + (base + s1) * CDIM + c);
    a0 += w0 * u.x + w1 * v.x; a1 += w0 * u.y + w1 * v.y;
    a2 += w0 * u.z + w1 * v.z; a3 += w0 * u.w + w1 * v.w;
  }
  uint2 o;
  o.x = (unsigned)f2bf(a0) | ((unsigned)f2bf(a1) << 16);
  o.y = (unsigned)f2bf(a2) | ((unsigned)f2bf(a3) << 16);
  *(uint2*)(Xa + (base + n) * CDIM + c) = o;
}

// bf16 source: 256 thr = 4 batch-slots x 64 lanes x 4 ch (uint2 8B loads)
__global__ __launch_bounds__(256) void agg_bf16(const unsigned short* __restrict__ X,
                                                const int* __restrict__ off,
                                                const int* __restrict__ srcv,
                                                const float* __restrict__ wv,
                                                unsigned short* __restrict__ Xa) {
  const int perx = gridDim.x >> 3;              // grid = 1700 * (B/4), %8 == 0
  const int gidx = (blockIdx.x & 7) * perx + (blockIdx.x >> 3);
  const int g = gidx / NNODES;                  // batch-group (4 batches)
  const int n = gidx - g * NNODES;
  const int b = g * 4 + (threadIdx.x >> 6);
  const int c = (threadIdx.x & 63) * 4;
  const int beg = off[n], end = off[n + 1];
  const size_t base = (size_t)b * NNODES;

  float a0 = 0.f, a1 = 0.f, a2 = 0.f, a3 = 0.f;
  for (int i = beg; i < end; i += 2) {
    int s0 = srcv[i];
    float w0 = wv[i];
    const bool two = (i + 1 < end);
    int i1 = two ? i + 1 : i;
    int s1 = srcv[i1];
    float w1 = two ? wv[i1] : 0.f;
    uint2 u = *(const uint2*)(X + (base + s0) * CDIM + c);
    uint2 v = *(const uint2*)(X + (base + s1) * CDIM + c);
    a0 += w0 * bf2f(u.x & 0xffffu) + w1 * bf2f(v.x & 0xffffu);
    a1 += w0 * bf2f(u.x >> 16)     + w1 * bf2f(v.x >> 16);
    a2 += w0 * bf2f(u.y & 0xffffu) + w1 * bf2f(v.y & 0xffffu);
    a3 += w0 * bf2f(u.y >> 16)     + w1 * bf2f(v.y >> 16);
  }
  uint2 o;
  o.x = (unsigned)f2bf(a0) | ((unsigned)f2bf(a1) << 16);
  o.y = (unsigned)f2bf(a2) | ((unsigned)f2bf(a3) << 16);
  *(uint2*)(Xa + (base + n) * CDIM + c) = o;
}

// ---------------- GEMM: out = epilogue( Xa[M][256] @ W ) -----------------------------------
// R5's proven gemm_t64 (BM=128 x BN=64, 4 waves 2x2, double-buffered counted-vmcnt pipeline,
// ~5 blocks/CU of independent sync domains) + NEW: LDS-staged C-write for non-FINAL layers.
// Direct bf16 stores were 32B segments (2x HBM write amplification, R4/R6 counters); staging
// the 128x64 tile in LDS (stride 72, reusing the dead K-loop buffers) and writing back
// row-major gives 128B-contiguous stores. FINAL keeps direct f32 stores (64B segs, clean).

template <int K>
__device__ __forceinline__ void kstep(const unsigned short* __restrict__ asrc,
                                      const unsigned short* __restrict__ bsrc,
                                      unsigned short* SH,
                                      int t, int wm, int wn, int lr, int lk,
                                      f32x4 (&acc)[4][2]) {
  if constexpr (K < 7) {
    asm volatile("s_waitcnt vmcnt(3)" ::: "memory");  // stage K done; K+1 (3) in flight
  } else {
    asm volatile("s_waitcnt vmcnt(0)" ::: "memory");
  }
  __builtin_amdgcn_s_barrier();  // stage K visible to all waves
  bf16x8 a[4], b[2];
#pragma unroll
  for (int i = 0; i < 4; i++)
    a[i] = *(const bf16x8*)&SH[(K & 1) * 4096 + (wm + i * 16 + lr) * 32 + lk];
#pragma unroll
  for (int i = 0; i < 2; i++)
    b[i] = *(const bf16x8*)&SH[8192 + (K & 1) * 2048 + (wn + i * 16 + lr) * 32 + lk];
  asm volatile("s_waitcnt lgkmcnt(0)" ::: "memory");  // reads landed in regs
  __builtin_amdgcn_sched_barrier(0);                  // rule #18 guard
  __builtin_amdgcn_s_barrier();  // all waves done reading buf K&1 -> safe to overwrite
  if constexpr (K + 2 < 8) {
    constexpr int S = K + 2;
    async_copy16(asrc + S * 32, &SH[(S & 1) * 4096 + t * 8]);
    async_copy16(asrc + (size_t)64 * CDIM + S * 32, &SH[(S & 1) * 4096 + 2048 + t * 8]);
    async_copy16(bsrc + S * 32, &SH[8192 + (S & 1) * 2048 + t * 8]);
  }
#pragma unroll
  for (int mi = 0; mi < 4; mi++)
#pragma unroll
    for (int ni = 0; ni < 2; ni++)
      acc[mi][ni] = __builtin_amdgcn_mfma_f32_16x16x32_bf16(a[mi], b[ni], acc[mi][ni], 0, 0, 0);
}

template <bool FINAL>
__global__ __launch_bounds__(256, 5) void gemm_t64(const unsigned short* __restrict__ A,
                                                   const unsigned short* __restrict__ Wt,
                                                   const float* __restrict__ bias,
                                                   const float* __restrict__ resid,
                                                   void* __restrict__ outp) {
  // SH: [0,8192) = As dbuf (2 x 128x32), [8192,12288) = Bs dbuf (2 x 64x32); 24 KB.
  // After the K-loop, reused as C staging [128][72] bf16 (9216 elems).
  __shared__ __align__(16) unsigned short SH[12288];
  const int t = threadIdx.x;
  const int lane = t & 63;
  const int w = t >> 6;
  const int wm = (w & 1) * 64;
  const int wn = (w >> 1) * 32;
  const int lr = lane & 15;
  const int lk = (lane >> 4) * 8;

  // bijective XCD swizzle (grid % 8 == 0)
  const int chunk = gridDim.x >> 3;
  const int swz = (blockIdx.x & 7) * chunk + (blockIdx.x >> 3);
  const int m0 = (swz >> 2) * 128;  // n-fastest: 4 n-siblings adjacent -> same XCD
  const int n0 = (swz & 3) * 64;

  const unsigned short* asrc = A + (size_t)(m0 + (t >> 2)) * CDIM + (t & 3) * 8;
  const unsigned short* bsrc = Wt + (size_t)(n0 + (t >> 2)) * CDIM + (t & 3) * 8;

  f32x4 acc[4][2] = {};

#pragma unroll
  for (int s = 0; s < 2; s++) {  // prologue: stages 0,1 in flight (3 loads each)
    async_copy16(asrc + s * 32, &SH[s * 4096 + t * 8]);
    async_copy16(asrc + (size_t)64 * CDIM + s * 32, &SH[s * 4096 + 2048 + t * 8]);
    async_copy16(bsrc + s * 32, &SH[8192 + s * 2048 + t * 8]);
  }

  kstep<0>(asrc, bsrc, SH, t, wm, wn, lr, lk, acc);
  kstep<1>(asrc, bsrc, SH, t, wm, wn, lr, lk, acc);
  kstep<2>(asrc, bsrc, SH, t, wm, wn, lr, lk, acc);
  kstep<3>(asrc, bsrc, SH, t, wm, wn, lr, lk, acc);
  kstep<4>(asrc, bsrc, SH, t, wm, wn, lr, lk, acc);
  kstep<5>(asrc, bsrc, SH, t, wm, wn, lr, lk, acc);
  kstep<6>(asrc, bsrc, SH, t, wm, wn, lr, lk, acc);
  kstep<7>(asrc, bsrc, SH, t, wm, wn, lr, lk, acc);

  float bv[2];
#pragma unroll
  for (int ni = 0; ni < 2; ni++) bv[ni] = bias[n0 + wn + ni * 16 + lr];
  const int orow = (lane >> 4) * 4;  // C/D: col=lane&15, row=(lane>>4)*4+r  [m89/m91]

  if (FINAL) {
    // direct f32 stores: 16 lanes x 4B = 64B segments, sector-clean
#pragma unroll
    for (int mi = 0; mi < 4; mi++) {
#pragma unroll
      for (int ni = 0; ni < 2; ni++) {
#pragma unroll
        for (int r = 0; r < 4; r++) {
          const size_t gr = (size_t)(m0 + wm + mi * 16 + orow + r);
          const size_t idx = gr * CDIM + n0 + wn + ni * 16 + lr;
          float v = acc[mi][ni][r] + bv[ni] + resid[idx];
          ((float*)outp)[idx] = fmaxf(v, 0.f);
        }
      }
    }
  } else {
    // LDS-staged bf16 C-write: stage [128][72] (pad kills quarter-wave bank aliasing),
    // read back row-major, store 128B-contiguous rows.
    __syncthreads();  // all waves fully past K-loop LDS use
#pragma unroll
    for (int mi = 0; mi < 4; mi++)
#pragma unroll
      for (int ni = 0; ni < 2; ni++)
#pragma unroll
        for (int r = 0; r < 4; r++) {
          const int row = wm + mi * 16 + orow + r;
          const int col = wn + ni * 16 + lr;
          SH[row * 72 + col] = f2bf(fmaxf(acc[mi][ni][r] + bv[ni], 0.f));
        }
    __syncthreads();
    unsigned short* O = (unsigned short*)outp;
#pragma unroll
    for (int q = 0; q < 4; q++) {
      const int cch = q * 256 + t;            // chunk id in [0,1024)
      const int row = cch >> 3, j = cch & 7;  // 8 x 16B chunks per 64-col row
      bf16x8 v = *(const bf16x8*)&SH[row * 72 + j * 8];
      *(bf16x8*)(O + (size_t)(m0 + row) * CDIM + n0 + j * 8) = v;
    }
  }
}

// ---------------- launch ----------------

extern "C" void kernel_launch(void* const* d_in, const int* in_sizes, int n_in,
                              void* d_out, int out_size, void* d_ws, size_t ws_size,
                              hipStream_t stream) {
  const float* x  = (const float*)d_in[0];
  const float* W1 = (const float*)d_in[1];
  const float* b1 = (const float*)d_in[2];
  const float* W2 = (const float*)d_in[3];
  const float* b2 = (const float*)d_in[4];
  const float* W3 = (const float*)d_in[5];
  const float* b3 = (const float*)d_in[6];
  const int* esp = (const int*)d_in[7];
  const int* etm = (const int*)d_in[8];

  const int Esp = in_sizes[7] / 2;
  const int Etm = in_sizes[8] / 2;
  const int B = in_sizes[0] / (NNODES * CDIM);
  const int M = B * NNODES;

  char* ws = (char*)d_ws;
  size_t woff = 0;
  auto alloc = [&](size_t bytes) -> void* {
    void* p = ws + woff;
    woff = (woff + bytes + 255) & ~(size_t)255;
    return p;
  };

  unsigned short* H   = (unsigned short*)alloc((size_t)M * CDIM * 2);  // 55.7 MB bf16
  unsigned short* Act = (unsigned short*)alloc((size_t)M * CDIM * 2);  // 55.7 MB bf16
  unsigned short* Wt  = (unsigned short*)alloc((size_t)3 * CDIM * CDIM * 2);
  int* zero_base = (int*)alloc((size_t)4 * NNODES * sizeof(int));
  int* cnt_sp = zero_base;
  int* cur_sp = zero_base + NNODES;
  int* cnt_tm = zero_base + 2 * NNODES;
  int* cur_tm = zero_base + 3 * NNODES;
  int* off_sp = (int*)alloc((NNODES + 1) * sizeof(int));
  int* off_tm = (int*)alloc((NNODES + 1) * sizeof(int));
  float* dinv_sp = (float*)alloc(NNODES * sizeof(float));
  float* dinv_tm = (float*)alloc(NNODES * sizeof(float));
  int*   src_sp = (int*)alloc((size_t)(Esp + NNODES) * sizeof(int));
  float* wgt_sp = (float*)alloc((size_t)(Esp + NNODES) * sizeof(float));
  int*   src_tm = (int*)alloc((size_t)(Etm + NNODES) * sizeof(int));
  float* wgt_tm = (float*)alloc((size_t)(Etm + NNODES) * sizeof(float));

  // graph preprocessing: 4 launches
  prep1<<<(3 * 65536 + 255) / 256, 256, 0, stream>>>(W1, W2, W3, Wt, zero_base);
  prep2<<<(Esp + Etm + 255) / 256, 256, 0, stream>>>(esp, Esp, etm, Etm, cnt_sp, cnt_tm);
  prep3<<<2, 1024, 0, stream>>>(cnt_sp, dinv_sp, off_sp, cnt_tm, dinv_tm, off_tm);
  prep4<<<(Esp + Etm + 2 * NNODES + 255) / 256, 256, 0, stream>>>(
      esp, Esp, etm, Etm, dinv_sp, off_sp, cur_sp, src_sp, wgt_sp,
      dinv_tm, off_tm, cur_tm, src_tm, wgt_tm);

  dim3 agrid_f(NNODES * (B / 2));   // 54400 blocks x 128 thr; /8 per XCD (4 groups of 2 slabs)
  dim3 agrid_b(NNODES * (B / 4));   // 27200 blocks x 256 thr; /8 per XCD (2 groups of 4 slabs)
  dim3 ggrid(4 * (M / 128));        // 3400: (850 m) x (4 n), n fastest, XCD-swizzled

  // layer 1 (spatial): Xa1 = A_hat x (f32 gather); out1 = relu(Xa1 W1 + b1) -> bf16 H
  agg_f32<<<agrid_f, 128, 0, stream>>>(x, off_sp, src_sp, wgt_sp, Act);
  gemm_t64<false><<<ggrid, 256, 0, stream>>>(Act, Wt, b1, nullptr, H);
  // layer 2 (temporal)
  agg_bf16<<<agrid_b, 256, 0, stream>>>(H, off_tm, src_tm, wgt_tm, Act);
  gemm_t64<false><<<ggrid, 256, 0, stream>>>(Act, Wt + CDIM * CDIM, b2, nullptr, H);
  // layer 3 (spatial) + residual + relu -> f32 d_out
  agg_bf16<<<agrid_b, 256, 0, stream>>>(H, off_sp, src_sp, wgt_sp, Act);
  gemm_t64<true><<<ggrid, 256, 0, stream>>>(Act, Wt + 2 * CDIM * CDIM, b3, x, d_out);
}